// Round 14
// baseline (439.533 us; speedup 1.0000x reference)
//
#include <hip/hip_runtime.h>
#include <hip/hip_bf16.h>

typedef __bf16 bf16x8 __attribute__((ext_vector_type(8)));
typedef float  f32x4  __attribute__((ext_vector_type(4)));
typedef unsigned short u16;
typedef unsigned int   u32;
typedef unsigned int   u32x2 __attribute__((ext_vector_type(2)));
typedef unsigned int   u32x4 __attribute__((ext_vector_type(4)));
typedef unsigned long long u64;

#define NB 1024
#define NS 1024
#define NI 32
#define NH 128
#define NCH (NS / 8)

// Pack 4 f32 -> 4 bf16 (RNE) in 2 VALU.
__device__ __forceinline__ u64 pack4_bf16(f32x4 v) {
  u32 lo, hi;
  asm("v_cvt_pk_bf16_f32 %0, %1, %2" : "=v"(lo) : "v"(v[0]), "v"(v[1]));
  asm("v_cvt_pk_bf16_f32 %0, %1, %2" : "=v"(hi) : "v"(v[2]), "v"(v[3]));
  u32x2 p; p[0] = lo; p[1] = hi;
  return __builtin_bit_cast(u64, p);
}

// Pack 8 f32 -> bf16x8 (RNE) in 4 VALU.
__device__ __forceinline__ bf16x8 cvt8pk(f32x4 a, f32x4 b) {
  u32x4 p;
  asm("v_cvt_pk_bf16_f32 %0, %1, %2" : "=v"(p[0]) : "v"(a[0]), "v"(a[1]));
  asm("v_cvt_pk_bf16_f32 %0, %1, %2" : "=v"(p[1]) : "v"(a[2]), "v"(a[3]));
  asm("v_cvt_pk_bf16_f32 %0, %1, %2" : "=v"(p[2]) : "v"(b[0]), "v"(b[1]));
  asm("v_cvt_pk_bf16_f32 %0, %1, %2" : "=v"(p[3]) : "v"(b[2]), "v"(b[3]));
  return __builtin_bit_cast(bf16x8, p);
}

// Barrier that drains lgkmcnt only (no vmcnt): global stores stay in flight.
__device__ __forceinline__ void lds_barrier() {
  __builtin_amdgcn_sched_barrier(0);
  asm volatile("s_waitcnt lgkmcnt(0)" ::: "memory");
  __builtin_amdgcn_s_barrier();
  asm volatile("" ::: "memory");
  __builtin_amdgcn_sched_barrier(0);
}

// Block: 512 threads = 8 waves (2/SIMD). Block owns 16 batch rows for the scan.
// Wave w computes hidden cols [16w, 16w+16).   (R13 skeleton = best known.)
// MFMA: D'[n][m] = sum_k U[k][n] * h[m][k]  (A' = U^T slice, B' = h^T)
//   B'-frag: lane l holds h[m=l&15][k = 32kt + 8(l>>4) + j]   (one ds_read_b128)
//   D'     : lane l holds h_new[m=l&15][n = 16w + 4(l>>4) + r]
// h ping-pongs in LDS as bf16, u64 units swizzled by unit ^ ((row&7)<<1).
// EXP-SCALE FOLD: z-gate weights/bias pre-scaled by -log2(e), h-gate by 2*log2(e):
//   e = exp2(min(az', 60)), f = exp2(min(ah', 43.35))
//   h' = h + [(f-1) - h(f+1)] / [(1+e)(f+1)]
// Reciprocals PAIRED: 1/d0 = rcp(d0*d1)*d1 (2 rcp per f32x4 instead of 4).
// az' cap 60 keeps d0*d1 finite (2^104 max); cap only binds when z ~= 0 -> h'=h.
__global__ __launch_bounds__(512, 2) void gru_scan(
    const float* __restrict__ x,
    const float* __restrict__ Wz, const float* __restrict__ Uz, const float* __restrict__ bz,
    const float* __restrict__ Wh, const float* __restrict__ Uh, const float* __restrict__ bh,
    float* __restrict__ out)
{
  __shared__ __align__(16) u64    hbuf[2][16][32];       // 8 KB
  __shared__ __align__(16) bf16x8 xbuf[2][8][16][4];     // 16 KB

  const int tid  = threadIdx.x;
  const int lane = tid & 63;
  const int w    = tid >> 6;     // wave 0..7
  const int ml   = lane & 15;    // batch row in tile
  const int g    = lane >> 4;    // k-group / reg-group
  const int rb   = blockIdx.x * 16;

  // ---- persistent weight fragments, pre-scaled per gate ----
  bf16x8 ufrag[2][4];   // [gate][kt]
  bf16x8 wfrag[2];      // [gate]
  f32x4  bias2[2];      // [gate], D layout
  {
    const float* Ug[2] = {Uz, Uh};
    const float* Wg[2] = {Wz, Wh};
    const float* bg[2] = {bz, bh};
    const float  gs[2] = {-1.4426950408889634f, 2.8853900817779268f};
    const int n0 = 16 * w + ml;   // A'-row = hidden col
#pragma unroll
    for (int gate = 0; gate < 2; ++gate) {
#pragma unroll
      for (int kt = 0; kt < 4; ++kt)
#pragma unroll
        for (int j = 0; j < 8; ++j)
          ufrag[gate][kt][j] = (__bf16)(Ug[gate][(32 * kt + 8 * g + j) * NH + n0] * gs[gate]);
#pragma unroll
      for (int j = 0; j < 8; ++j)
        wfrag[gate][j] = (__bf16)(Wg[gate][(8 * g + j) * NH + n0] * gs[gate]);
      const int nb = 16 * w + 4 * g;
#pragma unroll
      for (int r = 0; r < 4; ++r) bias2[gate][r] = bg[gate][nb + r] * gs[gate];
    }
  }

  // h0 = 0
  for (int i = tid; i < 16 * 32; i += 512) hbuf[0][i >> 5][i & 31] = 0ULL;

  // ---- x staging: thread (r_st, c8) handles 8 consecutive floats (one 16B unit) ----
  const int r_st  = tid >> 5;          // 0..15
  const int c8    = tid & 31;          // 0..31 -> tt = c8>>2, unit = c8&3
  const int tt_st = c8 >> 2;
  const int un_st = (c8 & 3) ^ (r_st & 3);
  const float* xbase = x + (size_t)(rb + r_st) * (NS * NI) + c8 * 8;

  {  // stage chunk 0
    f32x4 a0 = *(const f32x4*)(xbase);
    f32x4 a1 = *(const f32x4*)(xbase + 4);
    xbuf[0][tt_st][r_st][un_st] = cvt8pk(a0, a1);
  }
  __syncthreads();   // cold path: full drain fine

  // per-lane LDS constants
  const int sw = (ml & 7) << 1;
  int ridx[4];
#pragma unroll
  for (int kt = 0; kt < 4; ++kt) ridx[kt] = (8 * kt + 2 * g) ^ sw;  // even -> b128 ok
  const int widx = (4 * w + g) ^ sw;
  const int xidx = g ^ (ml & 3);

  f32x4 hv = {0.f, 0.f, 0.f, 0.f};
  float* optr = out + (size_t)(rb + ml) * NS * NH + 16 * w + 4 * g;

  f32x4 vxa, vxb;  // x global prefetch regs
  const f32x4 one4   = {1.f, 1.f, 1.f, 1.f};
  const f32x4 cap60  = {60.f, 60.f, 60.f, 60.f};
  const f32x4 clamp4 = {43.35f, 43.35f, 43.35f, 43.35f};   // 15.02 * 2*log2(e)

  // ax (= scaled bias + x@W') for t = 0
  f32x4 axz, axh;
  {
    bf16x8 xf = xbuf[0][0][ml][xidx];
    axz = __builtin_amdgcn_mfma_f32_16x16x32_bf16(wfrag[0], xf, bias2[0], 0, 0, 0);
    axh = __builtin_amdgcn_mfma_f32_16x16x32_bf16(wfrag[1], xf, bias2[1], 0, 0, 0);
  }

  // One step. P, XB, TT all compile-time. Consumes ax(t); produces ax(t+1).
#define GRU_STEP(P, XB, TT, DO_STORE, DO_STAGE)                                            \
  {                                                                                        \
    /* read burst: x frag (t+1) FIRST, then 4 h frags (t) */                               \
    bf16x8 xf  = xbuf[((TT) == 7) ? ((XB) ^ 1) : (XB)][((TT) + 1) & 7][ml][xidx];          \
    const u64* hrow = &hbuf[P][ml][0];                                                     \
    bf16x8 hf0 = *(const bf16x8*)(hrow + ridx[0]);                                         \
    bf16x8 hf1 = *(const bf16x8*)(hrow + ridx[1]);                                         \
    bf16x8 hf2 = *(const bf16x8*)(hrow + ridx[2]);                                         \
    bf16x8 hf3 = *(const bf16x8*)(hrow + ridx[3]);                                         \
    /* ax(t+1): depends only on xf -> issues during the h-read latency */                  \
    f32x4 axzn = __builtin_amdgcn_mfma_f32_16x16x32_bf16(wfrag[0], xf, bias2[0], 0, 0, 0); \
    f32x4 axhn = __builtin_amdgcn_mfma_f32_16x16x32_bf16(wfrag[1], xf, bias2[1], 0, 0, 0); \
    /* h-MFMAs: 2 chains, 4-deep accumulation (C-in = ax(t)) */                            \
    f32x4 cz = __builtin_amdgcn_mfma_f32_16x16x32_bf16(ufrag[0][0], hf0, axz, 0, 0, 0);    \
    f32x4 ch = __builtin_amdgcn_mfma_f32_16x16x32_bf16(ufrag[1][0], hf0, axh, 0, 0, 0);    \
    cz = __builtin_amdgcn_mfma_f32_16x16x32_bf16(ufrag[0][1], hf1, cz, 0, 0, 0);           \
    ch = __builtin_amdgcn_mfma_f32_16x16x32_bf16(ufrag[1][1], hf1, ch, 0, 0, 0);           \
    cz = __builtin_amdgcn_mfma_f32_16x16x32_bf16(ufrag[0][2], hf2, cz, 0, 0, 0);           \
    ch = __builtin_amdgcn_mfma_f32_16x16x32_bf16(ufrag[1][2], hf2, ch, 0, 0, 0);           \
    cz = __builtin_amdgcn_mfma_f32_16x16x32_bf16(ufrag[0][3], hf3, cz, 0, 0, 0);           \
    ch = __builtin_amdgcn_mfma_f32_16x16x32_bf16(ufrag[1][3], hf3, ch, 0, 0, 0);           \
    axz = axzn; axh = axhn;                                                                \
    /* fused elem: 8 exp2 + 2 paired rcp */                                                \
    f32x4 zcl = __builtin_elementwise_min(cz, cap60);                                      \
    f32x4 bcl = __builtin_elementwise_min(ch, clamp4);                                     \
    f32x4 e, f;                                                                            \
    _Pragma("unroll")                                                                      \
    for (int r = 0; r < 4; ++r) {                                                          \
      e[r] = __builtin_amdgcn_exp2f(zcl[r]);                                               \
      f[r] = __builtin_amdgcn_exp2f(bcl[r]);                                               \
    }                                                                                      \
    f32x4 fp  = f + one4;                                                                  \
    f32x4 num = (f - one4) - hv * fp;                                                      \
    f32x4 den = (e + one4) * fp;                                                           \
    float p01 = den[0] * den[1];                                                           \
    float p23 = den[2] * den[3];                                                           \
    float r01 = __builtin_amdgcn_rcpf(p01);                                                \
    float r23 = __builtin_amdgcn_rcpf(p23);                                                \
    f32x4 rr;                                                                              \
    rr[0] = r01 * den[1]; rr[1] = r01 * den[0];                                            \
    rr[2] = r23 * den[3]; rr[3] = r23 * den[2];                                            \
    f32x4 hn = num * rr + hv;                                                              \
    hv = hn;                                                                               \
    /* publish bf16 h(t+1) FIRST (critical for next step's ds_read) */                     \
    hbuf[P ^ 1][ml][widx] = pack4_bf16(hn);                                                \
    if (DO_STAGE) {  /* convert + write next x chunk (compile-time XB^1) */                \
      xbuf[(XB) ^ 1][tt_st][r_st][un_st] = cvt8pk(vxa, vxb);                               \
    }                                                                                      \
    /* stream hidden_seq[b, t, :] — stays in flight across the barrier */                  \
    if (DO_STORE) { __builtin_nontemporal_store(hn, (f32x4*)optr); optr += NH; }           \
    lds_barrier();                                                                         \
  }

  // Chunk body: XB compile-time; loads issued at tt0, staged at tt6.
#define CHUNK_BODY(XB, CHUNK, MORE)                                                        \
  {                                                                                        \
    if (MORE) {                                                                            \
      const float* p = xbase + (size_t)((CHUNK) + 1) * (8 * NI);                           \
      vxa = *(const f32x4*)(p); vxb = *(const f32x4*)(p + 4);                              \
    }                                                                                      \
    GRU_STEP(0, XB, 0, true, false)                                                        \
    GRU_STEP(1, XB, 1, true, false)                                                        \
    GRU_STEP(0, XB, 2, true, false)                                                        \
    GRU_STEP(1, XB, 3, true, false)                                                        \
    GRU_STEP(0, XB, 4, true, false)                                                        \
    GRU_STEP(1, XB, 5, true, false)                                                        \
    GRU_STEP(0, XB, 6, true, (MORE))                                                       \
    GRU_STEP(1, XB, 7, true, false)                                                        \
  }

  for (int cp = 0; cp < NCH / 2; ++cp) {
    const int  c0 = 2 * cp;
    const bool m1 = (c0 + 2 < NCH);
    CHUNK_BODY(0, c0,     true)   // even chunk: chunk+1 always exists
    CHUNK_BODY(1, c0 + 1, m1)     // odd chunk
  }

  // h_last
  const size_t lbase = (size_t)NB * NS * NH + (size_t)(rb + ml) * NH + 16 * w + 4 * g;
  *(f32x4*)(out + lbase) = hv;
}

extern "C" void kernel_launch(void* const* d_in, const int* in_sizes, int n_in,
                              void* d_out, int out_size, void* d_ws, size_t ws_size,
                              hipStream_t stream) {
  const float* x  = (const float*)d_in[0];
  // d_in[1..3] = W_r, U_r, b_r: unused (r gate never affects the output)
  const float* Wz = (const float*)d_in[4];
  const float* Uz = (const float*)d_in[5];
  const float* bz = (const float*)d_in[6];
  const float* Wh = (const float*)d_in[7];
  const float* Uh = (const float*)d_in[8];
  const float* bh = (const float*)d_in[9];
  float* out = (float*)d_out;

  gru_scan<<<dim3(NB / 16), dim3(512), 0, stream>>>(x, Wz, Uz, bz, Wh, Uh, bh, out);
}

// Round 15
// 426.725 us; speedup vs baseline: 1.0300x; 1.0300x over previous
//
#include <hip/hip_runtime.h>
#include <hip/hip_bf16.h>

typedef __bf16 bf16x8 __attribute__((ext_vector_type(8)));
typedef float  f32x4  __attribute__((ext_vector_type(4)));
typedef unsigned short u16;
typedef unsigned int   u32;
typedef unsigned int   u32x2 __attribute__((ext_vector_type(2)));
typedef unsigned int   u32x4 __attribute__((ext_vector_type(4)));
typedef unsigned long long u64;

#define NB 1024
#define NS 1024
#define NI 32
#define NH 128
#define NCH (NS / 8)

// Pack 4 f32 -> 4 bf16 (RNE) in 2 VALU.
__device__ __forceinline__ u64 pack4_bf16(f32x4 v) {
  u32 lo, hi;
  asm("v_cvt_pk_bf16_f32 %0, %1, %2" : "=v"(lo) : "v"(v[0]), "v"(v[1]));
  asm("v_cvt_pk_bf16_f32 %0, %1, %2" : "=v"(hi) : "v"(v[2]), "v"(v[3]));
  u32x2 p; p[0] = lo; p[1] = hi;
  return __builtin_bit_cast(u64, p);
}

// Pack 8 f32 -> bf16x8 (RNE) in 4 VALU.
__device__ __forceinline__ bf16x8 cvt8pk(f32x4 a, f32x4 b) {
  u32x4 p;
  asm("v_cvt_pk_bf16_f32 %0, %1, %2" : "=v"(p[0]) : "v"(a[0]), "v"(a[1]));
  asm("v_cvt_pk_bf16_f32 %0, %1, %2" : "=v"(p[1]) : "v"(a[2]), "v"(a[3]));
  asm("v_cvt_pk_bf16_f32 %0, %1, %2" : "=v"(p[2]) : "v"(b[0]), "v"(b[1]));
  asm("v_cvt_pk_bf16_f32 %0, %1, %2" : "=v"(p[3]) : "v"(b[2]), "v"(b[3]));
  return __builtin_bit_cast(bf16x8, p);
}

// Barrier that drains lgkmcnt only (no vmcnt): global stores stay in flight.
__device__ __forceinline__ void lds_barrier() {
  __builtin_amdgcn_sched_barrier(0);
  asm volatile("s_waitcnt lgkmcnt(0)" ::: "memory");
  __builtin_amdgcn_s_barrier();
  asm volatile("" ::: "memory");
  __builtin_amdgcn_sched_barrier(0);
}

// Block: 512 threads = 8 waves (2/SIMD). Block owns 16 batch rows for the scan.
// Wave w computes hidden cols [16w, 16w+16).   (R13 skeleton = best known.)
// MFMA: D'[n][m] = sum_k U[k][n] * h[m][k]  (A' = U^T slice, B' = h^T)
//   B'-frag: lane l holds h[m=l&15][k = 32kt + 8(l>>4) + j]   (one ds_read_b128)
//   D'     : lane l holds h_new[m=l&15][n = 16w + 4(l>>4) + r]
// h ping-pongs in LDS as bf16, u64 units swizzled by unit ^ ((row&7)<<1).
// EXP-SCALE FOLD: z-gate weights/bias pre-scaled by -log2(e), h-gate by 2*log2(e),
// so the MFMA outputs are exp2-ready: e = exp2(az'), f = exp2(min(ah', 43.35)).
//   h' = h + [(f-1) - h(f+1)] / [(1+e)(f+1)]    (3 trans; verified absmax 0.0098)
// az' needs no clamp: e->inf => den->inf => rcp->0 => h'=h (graceful saturation).
__global__ __launch_bounds__(512, 2) void gru_scan(
    const float* __restrict__ x,
    const float* __restrict__ Wz, const float* __restrict__ Uz, const float* __restrict__ bz,
    const float* __restrict__ Wh, const float* __restrict__ Uh, const float* __restrict__ bh,
    float* __restrict__ out)
{
  __shared__ __align__(16) u64    hbuf[2][16][32];       // 8 KB
  __shared__ __align__(16) bf16x8 xbuf[2][8][16][4];     // 16 KB

  const int tid  = threadIdx.x;
  const int lane = tid & 63;
  const int w    = tid >> 6;     // wave 0..7
  const int ml   = lane & 15;    // batch row in tile
  const int g    = lane >> 4;    // k-group / reg-group
  const int rb   = blockIdx.x * 16;

  // ---- persistent weight fragments, pre-scaled per gate ----
  bf16x8 ufrag[2][4];   // [gate][kt]
  bf16x8 wfrag[2];      // [gate]
  f32x4  bias2[2];      // [gate], D layout
  {
    const float* Ug[2] = {Uz, Uh};
    const float* Wg[2] = {Wz, Wh};
    const float* bg[2] = {bz, bh};
    const float  gs[2] = {-1.4426950408889634f, 2.8853900817779268f};
    const int n0 = 16 * w + ml;   // A'-row = hidden col
#pragma unroll
    for (int gate = 0; gate < 2; ++gate) {
#pragma unroll
      for (int kt = 0; kt < 4; ++kt)
#pragma unroll
        for (int j = 0; j < 8; ++j)
          ufrag[gate][kt][j] = (__bf16)(Ug[gate][(32 * kt + 8 * g + j) * NH + n0] * gs[gate]);
#pragma unroll
      for (int j = 0; j < 8; ++j)
        wfrag[gate][j] = (__bf16)(Wg[gate][(8 * g + j) * NH + n0] * gs[gate]);
      const int nb = 16 * w + 4 * g;
#pragma unroll
      for (int r = 0; r < 4; ++r) bias2[gate][r] = bg[gate][nb + r] * gs[gate];
    }
  }

  // h0 = 0
  for (int i = tid; i < 16 * 32; i += 512) hbuf[0][i >> 5][i & 31] = 0ULL;

  // ---- x staging: thread (r_st, c8) handles 8 consecutive floats (one 16B unit) ----
  const int r_st  = tid >> 5;          // 0..15
  const int c8    = tid & 31;          // 0..31 -> tt = c8>>2, unit = c8&3
  const int tt_st = c8 >> 2;
  const int un_st = (c8 & 3) ^ (r_st & 3);
  const float* xbase = x + (size_t)(rb + r_st) * (NS * NI) + c8 * 8;

  {  // stage chunk 0
    f32x4 a0 = *(const f32x4*)(xbase);
    f32x4 a1 = *(const f32x4*)(xbase + 4);
    xbuf[0][tt_st][r_st][un_st] = cvt8pk(a0, a1);
  }
  __syncthreads();   // cold path: full drain fine

  // per-lane LDS constants
  const int sw = (ml & 7) << 1;
  int ridx[4];
#pragma unroll
  for (int kt = 0; kt < 4; ++kt) ridx[kt] = (8 * kt + 2 * g) ^ sw;  // even -> b128 ok
  const int widx = (4 * w + g) ^ sw;
  const int xidx = g ^ (ml & 3);

  f32x4 hv = {0.f, 0.f, 0.f, 0.f};
  float* optr = out + (size_t)(rb + ml) * NS * NH + 16 * w + 4 * g;

  f32x4 vxa, vxb;  // x global prefetch regs
  const f32x4 one4   = {1.f, 1.f, 1.f, 1.f};
  const f32x4 clamp4 = {43.35f, 43.35f, 43.35f, 43.35f};   // 15.02 * 2*log2(e)

  // ax (= scaled bias + x@W') for t = 0
  f32x4 axz, axh;
  {
    bf16x8 xf = xbuf[0][0][ml][xidx];
    axz = __builtin_amdgcn_mfma_f32_16x16x32_bf16(wfrag[0], xf, bias2[0], 0, 0, 0);
    axh = __builtin_amdgcn_mfma_f32_16x16x32_bf16(wfrag[1], xf, bias2[1], 0, 0, 0);
  }

  // One step. P, XB, TT all compile-time. Consumes ax(t); produces ax(t+1).
#define GRU_STEP(P, XB, TT, DO_STORE, DO_STAGE)                                            \
  {                                                                                        \
    /* post-barrier read burst: 4 h frags (t) + 1 x frag (t+1) */                          \
    const u64* hrow = &hbuf[P][ml][0];                                                     \
    bf16x8 hf0 = *(const bf16x8*)(hrow + ridx[0]);                                         \
    bf16x8 hf1 = *(const bf16x8*)(hrow + ridx[1]);                                         \
    bf16x8 hf2 = *(const bf16x8*)(hrow + ridx[2]);                                         \
    bf16x8 hf3 = *(const bf16x8*)(hrow + ridx[3]);                                         \
    bf16x8 xf  = xbuf[((TT) == 7) ? ((XB) ^ 1) : (XB)][((TT) + 1) & 7][ml][xidx];          \
    /* h-MFMAs: 2 chains, 4-deep accumulation (throughput-bound; no tail adds) */          \
    f32x4 cz = __builtin_amdgcn_mfma_f32_16x16x32_bf16(ufrag[0][0], hf0, axz, 0, 0, 0);    \
    f32x4 ch = __builtin_amdgcn_mfma_f32_16x16x32_bf16(ufrag[1][0], hf0, axh, 0, 0, 0);    \
    cz = __builtin_amdgcn_mfma_f32_16x16x32_bf16(ufrag[0][1], hf1, cz, 0, 0, 0);           \
    ch = __builtin_amdgcn_mfma_f32_16x16x32_bf16(ufrag[1][1], hf1, ch, 0, 0, 0);           \
    cz = __builtin_amdgcn_mfma_f32_16x16x32_bf16(ufrag[0][2], hf2, cz, 0, 0, 0);           \
    ch = __builtin_amdgcn_mfma_f32_16x16x32_bf16(ufrag[1][2], hf2, ch, 0, 0, 0);           \
    cz = __builtin_amdgcn_mfma_f32_16x16x32_bf16(ufrag[0][3], hf3, cz, 0, 0, 0);           \
    ch = __builtin_amdgcn_mfma_f32_16x16x32_bf16(ufrag[1][3], hf3, ch, 0, 0, 0);           \
    /* ax(t+1): independent, issues behind the h-chains */                                 \
    axz = __builtin_amdgcn_mfma_f32_16x16x32_bf16(wfrag[0], xf, bias2[0], 0, 0, 0);        \
    axh = __builtin_amdgcn_mfma_f32_16x16x32_bf16(wfrag[1], xf, bias2[1], 0, 0, 0);        \
    /* fused elem, packed-f32 vector algebra + 8 scalar trans + 4 rcp */                   \
    f32x4 bcl = __builtin_elementwise_min(ch, clamp4);                                     \
    f32x4 e, f;                                                                            \
    _Pragma("unroll")                                                                      \
    for (int r = 0; r < 4; ++r) {                                                          \
      e[r] = __builtin_amdgcn_exp2f(cz[r]);                                                \
      f[r] = __builtin_amdgcn_exp2f(bcl[r]);                                               \
    }                                                                                      \
    f32x4 fp  = f + one4;                                                                  \
    f32x4 num = (f - one4) - hv * fp;                                                      \
    f32x4 den = (e + one4) * fp;                                                           \
    f32x4 rr;                                                                              \
    _Pragma("unroll")                                                                      \
    for (int r = 0; r < 4; ++r) rr[r] = __builtin_amdgcn_rcpf(den[r]);                     \
    f32x4 hn = num * rr + hv;                                                              \
    hv = hn;                                                                               \
    /* publish bf16 h(t+1) FIRST (critical for next step's ds_read) */                     \
    hbuf[P ^ 1][ml][widx] = pack4_bf16(hn);                                                \
    if (DO_STAGE) {  /* convert + write next x chunk (compile-time XB^1) */                \
      xbuf[(XB) ^ 1][tt_st][r_st][un_st] = cvt8pk(vxa, vxb);                               \
    }                                                                                      \
    /* stream hidden_seq[b, t, :] — stays in flight across the barrier */                  \
    if (DO_STORE) { __builtin_nontemporal_store(hn, (f32x4*)optr); optr += NH; }           \
    lds_barrier();                                                                         \
  }

  // Chunk body: XB compile-time; loads issued at tt0, staged at tt6.
#define CHUNK_BODY(XB, CHUNK, MORE)                                                        \
  {                                                                                        \
    if (MORE) {                                                                            \
      const float* p = xbase + (size_t)((CHUNK) + 1) * (8 * NI);                           \
      vxa = *(const f32x4*)(p); vxb = *(const f32x4*)(p + 4);                              \
    }                                                                                      \
    GRU_STEP(0, XB, 0, true, false)                                                        \
    GRU_STEP(1, XB, 1, true, false)                                                        \
    GRU_STEP(0, XB, 2, true, false)                                                        \
    GRU_STEP(1, XB, 3, true, false)                                                        \
    GRU_STEP(0, XB, 4, true, false)                                                        \
    GRU_STEP(1, XB, 5, true, false)                                                        \
    GRU_STEP(0, XB, 6, true, (MORE))                                                       \
    GRU_STEP(1, XB, 7, true, false)                                                        \
  }

  for (int cp = 0; cp < NCH / 2; ++cp) {
    const int  c0 = 2 * cp;
    const bool m1 = (c0 + 2 < NCH);
    CHUNK_BODY(0, c0,     true)   // even chunk: chunk+1 always exists
    CHUNK_BODY(1, c0 + 1, m1)     // odd chunk
  }

  // h_last
  const size_t lbase = (size_t)NB * NS * NH + (size_t)(rb + ml) * NH + 16 * w + 4 * g;
  *(f32x4*)(out + lbase) = hv;
}

extern "C" void kernel_launch(void* const* d_in, const int* in_sizes, int n_in,
                              void* d_out, int out_size, void* d_ws, size_t ws_size,
                              hipStream_t stream) {
  const float* x  = (const float*)d_in[0];
  // d_in[1..3] = W_r, U_r, b_r: unused (r gate never affects the output)
  const float* Wz = (const float*)d_in[4];
  const float* Uz = (const float*)d_in[5];
  const float* bz = (const float*)d_in[6];
  const float* Wh = (const float*)d_in[7];
  const float* Uh = (const float*)d_in[8];
  const float* bh = (const float*)d_in[9];
  float* out = (float*)d_out;

  gru_scan<<<dim3(NB / 16), dim3(512), 0, stream>>>(x, Wz, Uz, bz, Wh, Uh, bh, out);
}

// Round 16
// 410.579 us; speedup vs baseline: 1.0705x; 1.0393x over previous
//
#include <hip/hip_runtime.h>
#include <hip/hip_bf16.h>

typedef __bf16 bf16x8 __attribute__((ext_vector_type(8)));
typedef float  f32x4  __attribute__((ext_vector_type(4)));
typedef unsigned short u16;
typedef unsigned int   u32;
typedef unsigned int   u32x2 __attribute__((ext_vector_type(2)));
typedef unsigned int   u32x4 __attribute__((ext_vector_type(4)));
typedef unsigned long long u64;

#define NB 1024
#define NS 1024
#define NI 32
#define NH 128
#define NCH (NS / 8)

// Pack 4 f32 -> 4 bf16 (RNE) in 2 VALU.
__device__ __forceinline__ u64 pack4_bf16(f32x4 v) {
  u32 lo, hi;
  asm("v_cvt_pk_bf16_f32 %0, %1, %2" : "=v"(lo) : "v"(v[0]), "v"(v[1]));
  asm("v_cvt_pk_bf16_f32 %0, %1, %2" : "=v"(hi) : "v"(v[2]), "v"(v[3]));
  u32x2 p; p[0] = lo; p[1] = hi;
  return __builtin_bit_cast(u64, p);
}

// Pack 8 f32 -> bf16x8 (RNE) in 4 VALU.
__device__ __forceinline__ bf16x8 cvt8pk(f32x4 a, f32x4 b) {
  u32x4 p;
  asm("v_cvt_pk_bf16_f32 %0, %1, %2" : "=v"(p[0]) : "v"(a[0]), "v"(a[1]));
  asm("v_cvt_pk_bf16_f32 %0, %1, %2" : "=v"(p[1]) : "v"(a[2]), "v"(a[3]));
  asm("v_cvt_pk_bf16_f32 %0, %1, %2" : "=v"(p[2]) : "v"(b[0]), "v"(b[1]));
  asm("v_cvt_pk_bf16_f32 %0, %1, %2" : "=v"(p[3]) : "v"(b[2]), "v"(b[3]));
  return __builtin_bit_cast(bf16x8, p);
}

// Barrier that drains lgkmcnt only (no vmcnt): global stores stay in flight.
__device__ __forceinline__ void lds_barrier() {
  __builtin_amdgcn_sched_barrier(0);
  asm volatile("s_waitcnt lgkmcnt(0)" ::: "memory");
  __builtin_amdgcn_s_barrier();
  asm volatile("" ::: "memory");
  __builtin_amdgcn_sched_barrier(0);
}

// Block: 512 threads = 8 waves (2/SIMD). Block owns 16 batch rows for the scan.
// Wave w computes hidden cols [16w, 16w+16).   (R13 skeleton = best known.)
// MFMA: D'[n][m] = sum_k U[k][n] * h[m][k]  (A' = U^T slice, B' = h^T)
//   B'-frag: lane l holds h[m=l&15][k = 32kt + 8(l>>4) + j]   (one ds_read_b128)
//   D'     : lane l holds h_new[m=l&15][n = 16w + 4(l>>4) + r]
// h ping-pongs in LDS as bf16, u64 units swizzled by unit ^ ((row&7)<<1).
// EXP-SCALE FOLD: z-gate weights/bias pre-scaled by -log2(e), h-gate by 2*log2(e),
// so the MFMA outputs are exp2-ready: e = exp2(az'), f = exp2(min(ah', 43.35)).
//   h' = h + [(f-1) - h(f+1)] / [(1+e)(f+1)]    (3 trans; verified absmax 0.0098)
// R16 single change vs R13: x-frag read FIRST and ax(t+1) MFMAs issued BEFORE the
// h-chains — they depend only on xf (first LDS return), so the matrix pipe starts
// ~40-80 cy earlier inside the h-read latency window.
__global__ __launch_bounds__(512, 2) void gru_scan(
    const float* __restrict__ x,
    const float* __restrict__ Wz, const float* __restrict__ Uz, const float* __restrict__ bz,
    const float* __restrict__ Wh, const float* __restrict__ Uh, const float* __restrict__ bh,
    float* __restrict__ out)
{
  __shared__ __align__(16) u64    hbuf[2][16][32];       // 8 KB
  __shared__ __align__(16) bf16x8 xbuf[2][8][16][4];     // 16 KB

  const int tid  = threadIdx.x;
  const int lane = tid & 63;
  const int w    = tid >> 6;     // wave 0..7
  const int ml   = lane & 15;    // batch row in tile
  const int g    = lane >> 4;    // k-group / reg-group
  const int rb   = blockIdx.x * 16;

  // ---- persistent weight fragments, pre-scaled per gate ----
  bf16x8 ufrag[2][4];   // [gate][kt]
  bf16x8 wfrag[2];      // [gate]
  f32x4  bias2[2];      // [gate], D layout
  {
    const float* Ug[2] = {Uz, Uh};
    const float* Wg[2] = {Wz, Wh};
    const float* bg[2] = {bz, bh};
    const float  gs[2] = {-1.4426950408889634f, 2.8853900817779268f};
    const int n0 = 16 * w + ml;   // A'-row = hidden col
#pragma unroll
    for (int gate = 0; gate < 2; ++gate) {
#pragma unroll
      for (int kt = 0; kt < 4; ++kt)
#pragma unroll
        for (int j = 0; j < 8; ++j)
          ufrag[gate][kt][j] = (__bf16)(Ug[gate][(32 * kt + 8 * g + j) * NH + n0] * gs[gate]);
#pragma unroll
      for (int j = 0; j < 8; ++j)
        wfrag[gate][j] = (__bf16)(Wg[gate][(8 * g + j) * NH + n0] * gs[gate]);
      const int nb = 16 * w + 4 * g;
#pragma unroll
      for (int r = 0; r < 4; ++r) bias2[gate][r] = bg[gate][nb + r] * gs[gate];
    }
  }

  // h0 = 0
  for (int i = tid; i < 16 * 32; i += 512) hbuf[0][i >> 5][i & 31] = 0ULL;

  // ---- x staging: thread (r_st, c8) handles 8 consecutive floats (one 16B unit) ----
  const int r_st  = tid >> 5;          // 0..15
  const int c8    = tid & 31;          // 0..31 -> tt = c8>>2, unit = c8&3
  const int tt_st = c8 >> 2;
  const int un_st = (c8 & 3) ^ (r_st & 3);
  const float* xbase = x + (size_t)(rb + r_st) * (NS * NI) + c8 * 8;

  {  // stage chunk 0
    f32x4 a0 = *(const f32x4*)(xbase);
    f32x4 a1 = *(const f32x4*)(xbase + 4);
    xbuf[0][tt_st][r_st][un_st] = cvt8pk(a0, a1);
  }
  __syncthreads();   // cold path: full drain fine

  // per-lane LDS constants
  const int sw = (ml & 7) << 1;
  int ridx[4];
#pragma unroll
  for (int kt = 0; kt < 4; ++kt) ridx[kt] = (8 * kt + 2 * g) ^ sw;  // even -> b128 ok
  const int widx = (4 * w + g) ^ sw;
  const int xidx = g ^ (ml & 3);

  f32x4 hv = {0.f, 0.f, 0.f, 0.f};
  float* optr = out + (size_t)(rb + ml) * NS * NH + 16 * w + 4 * g;

  f32x4 vxa, vxb;  // x global prefetch regs
  const f32x4 one4   = {1.f, 1.f, 1.f, 1.f};
  const f32x4 clamp4 = {43.35f, 43.35f, 43.35f, 43.35f};   // 15.02 * 2*log2(e)

  // ax (= scaled bias + x@W') for t = 0
  f32x4 axz, axh;
  {
    bf16x8 xf = xbuf[0][0][ml][xidx];
    axz = __builtin_amdgcn_mfma_f32_16x16x32_bf16(wfrag[0], xf, bias2[0], 0, 0, 0);
    axh = __builtin_amdgcn_mfma_f32_16x16x32_bf16(wfrag[1], xf, bias2[1], 0, 0, 0);
  }

  // One step. P, XB, TT all compile-time. Consumes ax(t); produces ax(t+1).
#define GRU_STEP(P, XB, TT, DO_STORE, DO_STAGE)                                            \
  {                                                                                        \
    /* read burst: x frag (t+1) FIRST, then 4 h frags (t) */                               \
    bf16x8 xf  = xbuf[((TT) == 7) ? ((XB) ^ 1) : (XB)][((TT) + 1) & 7][ml][xidx];          \
    const u64* hrow = &hbuf[P][ml][0];                                                     \
    bf16x8 hf0 = *(const bf16x8*)(hrow + ridx[0]);                                         \
    bf16x8 hf1 = *(const bf16x8*)(hrow + ridx[1]);                                         \
    bf16x8 hf2 = *(const bf16x8*)(hrow + ridx[2]);                                         \
    bf16x8 hf3 = *(const bf16x8*)(hrow + ridx[3]);                                         \
    /* ax(t+1): depends only on xf -> issues during the h-read latency */                  \
    f32x4 axzn = __builtin_amdgcn_mfma_f32_16x16x32_bf16(wfrag[0], xf, bias2[0], 0, 0, 0); \
    f32x4 axhn = __builtin_amdgcn_mfma_f32_16x16x32_bf16(wfrag[1], xf, bias2[1], 0, 0, 0); \
    /* h-MFMAs: 2 chains, 4-deep accumulation (C-in = ax(t)) */                            \
    f32x4 cz = __builtin_amdgcn_mfma_f32_16x16x32_bf16(ufrag[0][0], hf0, axz, 0, 0, 0);    \
    f32x4 ch = __builtin_amdgcn_mfma_f32_16x16x32_bf16(ufrag[1][0], hf0, axh, 0, 0, 0);    \
    cz = __builtin_amdgcn_mfma_f32_16x16x32_bf16(ufrag[0][1], hf1, cz, 0, 0, 0);           \
    ch = __builtin_amdgcn_mfma_f32_16x16x32_bf16(ufrag[1][1], hf1, ch, 0, 0, 0);           \
    cz = __builtin_amdgcn_mfma_f32_16x16x32_bf16(ufrag[0][2], hf2, cz, 0, 0, 0);           \
    ch = __builtin_amdgcn_mfma_f32_16x16x32_bf16(ufrag[1][2], hf2, ch, 0, 0, 0);           \
    cz = __builtin_amdgcn_mfma_f32_16x16x32_bf16(ufrag[0][3], hf3, cz, 0, 0, 0);           \
    ch = __builtin_amdgcn_mfma_f32_16x16x32_bf16(ufrag[1][3], hf3, ch, 0, 0, 0);           \
    axz = axzn; axh = axhn;                                                                \
    /* fused elem, packed-f32 vector algebra + 8 scalar trans + 4 rcp (R13 form) */        \
    f32x4 bcl = __builtin_elementwise_min(ch, clamp4);                                     \
    f32x4 e, f;                                                                            \
    _Pragma("unroll")                                                                      \
    for (int r = 0; r < 4; ++r) {                                                          \
      e[r] = __builtin_amdgcn_exp2f(cz[r]);                                                \
      f[r] = __builtin_amdgcn_exp2f(bcl[r]);                                               \
    }                                                                                      \
    f32x4 fp  = f + one4;                                                                  \
    f32x4 num = (f - one4) - hv * fp;                                                      \
    f32x4 den = (e + one4) * fp;                                                           \
    f32x4 rr;                                                                              \
    _Pragma("unroll")                                                                      \
    for (int r = 0; r < 4; ++r) rr[r] = __builtin_amdgcn_rcpf(den[r]);                     \
    f32x4 hn = num * rr + hv;                                                              \
    hv = hn;                                                                               \
    /* publish bf16 h(t+1) FIRST (critical for next step's ds_read) */                     \
    hbuf[P ^ 1][ml][widx] = pack4_bf16(hn);                                                \
    if (DO_STAGE) {  /* convert + write next x chunk (compile-time XB^1) */                \
      xbuf[(XB) ^ 1][tt_st][r_st][un_st] = cvt8pk(vxa, vxb);                               \
    }                                                                                      \
    /* stream hidden_seq[b, t, :] — stays in flight across the barrier */                  \
    if (DO_STORE) { __builtin_nontemporal_store(hn, (f32x4*)optr); optr += NH; }           \
    lds_barrier();                                                                         \
  }

  // Chunk body: XB compile-time; loads issued at tt0, staged at tt6.
#define CHUNK_BODY(XB, CHUNK, MORE)                                                        \
  {                                                                                        \
    if (MORE) {                                                                            \
      const float* p = xbase + (size_t)((CHUNK) + 1) * (8 * NI);                           \
      vxa = *(const f32x4*)(p); vxb = *(const f32x4*)(p + 4);                              \
    }                                                                                      \
    GRU_STEP(0, XB, 0, true, false)                                                        \
    GRU_STEP(1, XB, 1, true, false)                                                        \
    GRU_STEP(0, XB, 2, true, false)                                                        \
    GRU_STEP(1, XB, 3, true, false)                                                        \
    GRU_STEP(0, XB, 4, true, false)                                                        \
    GRU_STEP(1, XB, 5, true, false)                                                        \
    GRU_STEP(0, XB, 6, true, (MORE))                                                       \
    GRU_STEP(1, XB, 7, true, false)                                                        \
  }

  for (int cp = 0; cp < NCH / 2; ++cp) {
    const int  c0 = 2 * cp;
    const bool m1 = (c0 + 2 < NCH);
    CHUNK_BODY(0, c0,     true)   // even chunk: chunk+1 always exists
    CHUNK_BODY(1, c0 + 1, m1)     // odd chunk
  }

  // h_last
  const size_t lbase = (size_t)NB * NS * NH + (size_t)(rb + ml) * NH + 16 * w + 4 * g;
  *(f32x4*)(out + lbase) = hv;
}

extern "C" void kernel_launch(void* const* d_in, const int* in_sizes, int n_in,
                              void* d_out, int out_size, void* d_ws, size_t ws_size,
                              hipStream_t stream) {
  const float* x  = (const float*)d_in[0];
  // d_in[1..3] = W_r, U_r, b_r: unused (r gate never affects the output)
  const float* Wz = (const float*)d_in[4];
  const float* Uz = (const float*)d_in[5];
  const float* bz = (const float*)d_in[6];
  const float* Wh = (const float*)d_in[7];
  const float* Uh = (const float*)d_in[8];
  const float* bh = (const float*)d_in[9];
  float* out = (float*)d_out;

  gru_scan<<<dim3(NB / 16), dim3(512), 0, stream>>>(x, Wz, Uz, bz, Wh, Uh, bh, out);
}